// Round 1
// baseline (5642.993 us; speedup 1.0000x reference)
//
#include <hip/hip_runtime.h>
#include <hip/hip_bf16.h>
#include <math.h>

#define SEQL 70
#define NBATCH 16
#define NINPD 400
#define NHIDD 1150
#define NTOK 33278
#define ODE_STEPS 8

typedef __attribute__((ext_vector_type(4))) float f32x4;
typedef __attribute__((ext_vector_type(8))) short s16x8;
typedef unsigned short u16;

__device__ __forceinline__ u16 f2b(float f) {
    union { float f; unsigned int u; } a; a.f = f;
    unsigned int u = a.u;
    return (u16)((u + 0x7FFFu + ((u >> 16) & 1u)) >> 16);
}
__device__ __forceinline__ float b2f(u16 s) {
    union { unsigned int u; float f; } a; a.u = ((unsigned int)s) << 16;
    return a.f;
}

// ---------- prep kernels ----------
// dst[(g*Nop+j)*Kp + k] = bf16(src[(g*Nin+j)*rs + co + k]) padded with 0
__global__ void cvt_pad_k(const float* __restrict__ src, u16* __restrict__ dst,
                          int G, int Nin, int Nop, int Kin, int Kp, int rs, int co) {
    size_t total = (size_t)G * Nop * Kp;
    for (size_t idx = (size_t)blockIdx.x * 256 + threadIdx.x; idx < total;
         idx += (size_t)gridDim.x * 256) {
        int k = (int)(idx % Kp);
        size_t t2 = idx / Kp;
        int j = (int)(t2 % Nop);
        int g = (int)(t2 / Nop);
        float v = 0.f;
        if (j < Nin && k < Kin) v = src[((size_t)g * Nin + j) * rs + co + k];
        dst[idx] = f2b(v);
    }
}

__global__ void bias_k(const float* __restrict__ bih, const float* __restrict__ bhh,
                       float* __restrict__ o, int Nin, int Nop) {
    int idx = blockIdx.x * 256 + threadIdx.x;
    if (idx >= 4 * Nop) return;
    int g = idx / Nop, j = idx % Nop;
    o[idx] = (j < Nin) ? (bih[g * Nin + j] + bhh[g * Nin + j]) : 0.f;
}

__global__ void wtdwx_k(const float* __restrict__ cw, float* __restrict__ wt,
                        float* __restrict__ dwx) {
    int i = blockIdx.x * 256 + threadIdx.x;
    if (i < NINPD) {
        wt[i]  = cw[(size_t)i * (NINPD + 1)];
        dwx[i] = cw[(size_t)i * (NINPD + 1) + 1 + i];
    }
}

__global__ void h0cvt_k(const float* __restrict__ h0, u16* __restrict__ hb, int N, int Kp) {
    int idx = blockIdx.x * 256 + threadIdx.x;
    if (idx >= 16 * Kp) return;
    int b = idx / Kp, k = idx % Kp;
    hb[idx] = f2b(k < N ? h0[b * N + k] : 0.f);
}

__global__ void copyhc_k(const u16* __restrict__ hb, const float* __restrict__ cb,
                         float* __restrict__ oh, float* __restrict__ oc, int N, int Kp) {
    int idx = blockIdx.x * 256 + threadIdx.x;
    if (idx >= 16 * N) return;
    int b = idx / N, j = idx % N;
    oh[idx] = b2f(hb[b * Kp + j]);
    oc[idx] = cb[idx];
}

__global__ void embed_k(const int* __restrict__ tok, const float* __restrict__ emb,
                        u16* __restrict__ x0) {
    int idx = blockIdx.x * 256 + threadIdx.x;
    if (idx >= 1152 * 416) return;
    int r = idx / 416, k = idx - r * 416;
    float v = 0.f;
    if (r < SEQL * NBATCH && k < NINPD) v = emb[(size_t)tok[r] * NINPD + k];
    x0[idx] = f2b(v);
}

__global__ void rowsumsq_k(const float* __restrict__ X, float* __restrict__ o, int K) {
    int r = blockIdx.x;
    const float* xr = X + (size_t)r * K;
    int lane = threadIdx.x;
    float s = 0.f;
    for (int k = lane; k < K; k += 64) { float v = xr[k]; s += v * v; }
#pragma unroll
    for (int off = 1; off < 64; off <<= 1) s += __shfl_xor(s, off, 64);
    if (lane == 0) o[r] = s;
}

__global__ void ucomb_k(const float* __restrict__ e2, const float* __restrict__ dl,
                        float* __restrict__ u) {
    int i = blockIdx.x * 256 + threadIdx.x;
    if (i < NTOK) u[i] = -0.5f * e2[i] - dl[i];
}

// ---------- GEMM: C[M,N](fp32) = A[M,Kp](bf16) * B[N,Kp]^T(bf16) (+ u[n]) ----------
// grid.x = Npad/64, grid.y = Mpad/64 ; block 256 (4 waves, wave w -> m-tile w)
__global__ void gemm_bt_k(const u16* __restrict__ A, const u16* __restrict__ B,
                          float* __restrict__ C, int Kp, int lda, int ldb, int ldc,
                          int Mreal, int Nreal, const float* __restrict__ uvec) {
    const int tid = threadIdx.x;
    const int wid = tid >> 6, lane = tid & 63;
    const int la = lane & 15, lk = (lane >> 4) * 8;
    const int m0 = blockIdx.y * 64 + wid * 16;
    const int n0 = blockIdx.x * 64;
    const f32x4 Z4 = {0.f, 0.f, 0.f, 0.f};
    f32x4 acc[4] = {Z4, Z4, Z4, Z4};
    const u16* Ar = A + (size_t)(m0 + la) * lda + lk;
    const u16* Br = B + (size_t)(n0 + la) * ldb + lk;
    for (int k = 0; k < Kp; k += 32) {
        s16x8 a = *(const s16x8*)(Ar + k);
#pragma unroll
        for (int nt = 0; nt < 4; ++nt) {
            s16x8 b = *(const s16x8*)(Br + (size_t)nt * 16 * ldb + k);
            acc[nt] = __builtin_amdgcn_mfma_f32_16x16x32_bf16(a, b, acc[nt], 0, 0, 0);
        }
    }
    const int mr = m0 + (lane >> 4) * 4;
#pragma unroll
    for (int nt = 0; nt < 4; ++nt) {
        int cc = n0 + nt * 16 + la;
        if (cc >= Nreal) continue;
        float uv = uvec ? uvec[cc] : 0.f;
#pragma unroll
        for (int r = 0; r < 4; ++r) {
            int rr = mr + r;
            if (rr < Mreal) C[(size_t)rr * ldc + cc] = acc[nt][r] + uv;
        }
    }
}

// ---------- LSTM step: gates = h*Whh^T + xW(t) + bias ; activations ----------
// grid = Np/16 blocks; 4 waves = 4 gate types (i,f,g,o)
__global__ void lstm_step_k(const u16* __restrict__ hsrc, const u16* __restrict__ Whh,
                            const float* __restrict__ xW, const float* __restrict__ bias,
                            float* __restrict__ c, u16* __restrict__ hdst,
                            u16* __restrict__ ys, int N, int Np, int Kp, int Kp2) {
    __shared__ float gl[4][16][16];
    const int tid = threadIdx.x;
    const int wid = tid >> 6, lane = tid & 63;
    const int la = lane & 15, lk = (lane >> 4) * 8;
    const int jb = blockIdx.x;
    const f32x4 Z4 = {0.f, 0.f, 0.f, 0.f};
    f32x4 acc = Z4;
    const u16* Ar = hsrc + (size_t)la * Kp + lk;
    const u16* Br = Whh + (size_t)(wid * Np + jb * 16 + la) * Kp + lk;
    for (int k = 0; k < Kp; k += 32) {
        s16x8 a = *(const s16x8*)(Ar + k);
        s16x8 b = *(const s16x8*)(Br + k);
        acc = __builtin_amdgcn_mfma_f32_16x16x32_bf16(a, b, acc, 0, 0, 0);
    }
    const int col = jb * 16 + la;
    const int b4 = (lane >> 4) * 4;
#pragma unroll
    for (int r = 0; r < 4; ++r) {
        int bb = b4 + r;
        gl[wid][bb][la] = acc[r] + xW[(size_t)bb * (4 * Np) + wid * Np + col]
                          + bias[wid * Np + col];
    }
    __syncthreads();
    const int tb = tid >> 4, tj = tid & 15;
    const int j = jb * 16 + tj;
    if (j < N) {
        float gi = gl[0][tb][tj], gf = gl[1][tb][tj];
        float gg = gl[2][tb][tj], go = gl[3][tb][tj];
        float si = 1.f / (1.f + expf(-gi));
        float sf = 1.f / (1.f + expf(-gf));
        float so = 1.f / (1.f + expf(-go));
        float cn = sf * c[tb * N + j] + si * tanhf(gg);
        float hn = so * tanhf(cn);
        c[tb * N + j] = cn;
        u16 hb16 = f2b(hn);
        hdst[tb * Kp2 + j] = hb16;
        ys[tb * Kp2 + j] = hb16;
    }
}

// ---------- fused CNF (RK4, 8 steps, 4 stages each) ----------
// block = 64 emb rows (4 waves x 16-row m-tile), z resident in LDS
__global__ __launch_bounds__(256, 1) void cnf_k(const float* __restrict__ emb,
                                                const u16* __restrict__ Wxp,
                                                const float* __restrict__ wt,
                                                const float* __restrict__ bv,
                                                const float* __restrict__ dwx,
                                                float* __restrict__ dl) {
    __shared__ float zm[64][400];
    __shared__ u16 zi[64][416];
    const int tid = threadIdx.x;
    const int m0 = blockIdx.x * 64;
    for (int idx = tid; idx < 64 * 416; idx += 256) {
        int r = idx / 416, cc = idx - (idx / 416) * 416;
        float v = 0.f;
        int row = m0 + r;
        if (cc < 400 && row < NTOK) v = emb[(size_t)row * 400 + cc];
        if (cc < 400) zm[r][cc] = v;
        zi[r][cc] = f2b(v);
    }
    __syncthreads();
    const int lane = tid & 63, wid = tid >> 6;
    const int la = lane & 15, lk = (lane >> 4) * 8;
    const int mt = wid * 16;
    const int mrb = mt + ((lane >> 4) << 2);
    const float dt = 1.f / ODE_STEPS;
    const f32x4 Z4 = {0.f, 0.f, 0.f, 0.f};
    float divacc[4] = {0.f, 0.f, 0.f, 0.f};
#pragma unroll 1
    for (int st = 0; st < ODE_STEPS; ++st) {
        float t0 = st * dt;
        f32x4 acz[25];
#pragma unroll
        for (int nt = 0; nt < 25; ++nt) acz[nt] = Z4;
#pragma unroll 1
        for (int s = 0; s < 4; ++s) {
            float ts = t0 + ((s == 0) ? 0.f : (s == 3) ? dt : 0.5f * dt);
            float wgt = (s == 1 || s == 2) ? 2.f : 1.f;
            float cs = (s == 2) ? dt : 0.5f * dt;
            f32x4 pre[25];
#pragma unroll
            for (int nt = 0; nt < 25; ++nt) pre[nt] = Z4;
#pragma unroll 1
            for (int k = 0; k < 13; ++k) {
                s16x8 a = *(const s16x8*)(&zi[mt + la][k * 32 + lk]);
#pragma unroll
                for (int nt = 0; nt < 25; ++nt) {
                    s16x8 b = *(const s16x8*)(Wxp + (size_t)(nt * 16 + la) * 416 + k * 32 + lk);
                    pre[nt] = __builtin_amdgcn_mfma_f32_16x16x32_bf16(a, b, pre[nt], 0, 0, 0);
                }
            }
            __syncthreads();
#pragma unroll
            for (int nt = 0; nt < 25; ++nt) {
                int cc = nt * 16 + la;
                float wtc = wt[cc], bc = bv[cc], dw = dwx[cc] * wgt;
#pragma unroll
                for (int r = 0; r < 4; ++r) {
                    float pv = pre[nt][r] + ts * wtc + bc;
                    float kz = fmaxf(pv, 0.f);
                    if (pv > 0.f) divacc[r] += dw;
                    acz[nt][r] += wgt * kz;
                    if (s < 3) zi[mrb + r][cc] = f2b(zm[mrb + r][cc] + cs * kz);
                }
            }
            __syncthreads();
        }
#pragma unroll
        for (int nt = 0; nt < 25; ++nt) {
            int cc = nt * 16 + la;
#pragma unroll
            for (int r = 0; r < 4; ++r) {
                float zn = zm[mrb + r][cc] + (dt / 6.f) * acz[nt][r];
                zm[mrb + r][cc] = zn;
                zi[mrb + r][cc] = f2b(zn);
            }
        }
        __syncthreads();
    }
#pragma unroll
    for (int r = 0; r < 4; ++r) {
        float v = divacc[r];
        v += __shfl_xor(v, 1, 16);
        v += __shfl_xor(v, 2, 16);
        v += __shfl_xor(v, 4, 16);
        v += __shfl_xor(v, 8, 16);
        divacc[r] = v;
    }
    if (la == 0) {
#pragma unroll
        for (int r = 0; r < 4; ++r) {
            int row = m0 + mrb + r;
            if (row < NTOK) dl[row] = -(dt / 6.f) * divacc[r];
        }
    }
}

// ---------- in-place log(softmax(x)+1e-8) per row ----------
__global__ void logsoftmax_k(float* __restrict__ L, int n) {
    const int row = blockIdx.x;
    float* R = L + (size_t)row * n;
    const int tid = threadIdx.x;
    float mx = -INFINITY, s = 0.f;
    for (int c = tid; c < n; c += 256) {
        float v = R[c];
        float nm = fmaxf(mx, v);
        s = s * expf(mx - nm) + expf(v - nm);
        mx = nm;
    }
#pragma unroll
    for (int off = 1; off < 64; off <<= 1) {
        float om = __shfl_xor(mx, off, 64);
        float os = __shfl_xor(s, off, 64);
        float nm = fmaxf(mx, om);
        s = s * expf(mx - nm) + os * expf(om - nm);
        mx = nm;
    }
    __shared__ float smx[4], ssm[4];
    if ((tid & 63) == 0) { smx[tid >> 6] = mx; ssm[tid >> 6] = s; }
    __syncthreads();
    float bm = fmaxf(fmaxf(smx[0], smx[1]), fmaxf(smx[2], smx[3]));
    float bs = ssm[0] * expf(smx[0] - bm) + ssm[1] * expf(smx[1] - bm) +
               ssm[2] * expf(smx[2] - bm) + ssm[3] * expf(smx[3] - bm);
    float lz = logf(bs);
    for (int c = tid; c < n; c += 256) {
        float v = R[c];
        R[c] = logf(expf(v - bm) + 1e-8f * bs) - lz;
    }
}

extern "C" void kernel_launch(void* const* d_in, const int* in_sizes, int n_in,
                              void* d_out, int out_size, void* d_ws, size_t ws_size,
                              hipStream_t stream) {
    const int*   tokens = (const int*)d_in[0];
    const float* h00 = (const float*)d_in[1];
    const float* c00 = (const float*)d_in[2];
    const float* h01 = (const float*)d_in[3];
    const float* c01 = (const float*)d_in[4];
    const float* h02 = (const float*)d_in[5];
    const float* c02 = (const float*)d_in[6];
    const float* embW = (const float*)d_in[7];
    const float* Wih0 = (const float*)d_in[8];
    const float* Whh0 = (const float*)d_in[9];
    const float* bih0 = (const float*)d_in[10];
    const float* bhh0 = (const float*)d_in[11];
    const float* Wih1 = (const float*)d_in[12];
    const float* Whh1 = (const float*)d_in[13];
    const float* bih1 = (const float*)d_in[14];
    const float* bhh1 = (const float*)d_in[15];
    const float* Wih2 = (const float*)d_in[16];
    const float* Whh2 = (const float*)d_in[17];
    const float* bih2 = (const float*)d_in[18];
    const float* bhh2 = (const float*)d_in[19];
    const float* cnfW = (const float*)d_in[20];
    const float* cnfb = (const float*)d_in[21];
    float* out = (float*)d_out;

    // workspace carve
    char* p = (char*)d_ws;
    auto alloc = [&](size_t bytes) -> void* {
        void* r = (void*)p;
        p += (bytes + 255) & ~(size_t)255;
        return r;
    };
    u16*   emb_p = (u16*)alloc((size_t)33280 * 416 * 2);
    u16*   x0    = (u16*)alloc((size_t)1152 * 416 * 2);
    u16*   ys0   = (u16*)alloc((size_t)1152 * 1152 * 2);
    u16*   ys1   = (u16*)alloc((size_t)1152 * 1152 * 2);
    u16*   ys2   = (u16*)alloc((size_t)1152 * 416 * 2);
    float* xW    = (float*)alloc((size_t)1120 * 4608 * 4);
    u16*   Wih0p = (u16*)alloc((size_t)4608 * 416 * 2);
    u16*   Whh0p = (u16*)alloc((size_t)4608 * 1152 * 2);
    u16*   Wih1p = (u16*)alloc((size_t)4608 * 1152 * 2);
    u16*   Whh1p = (u16*)alloc((size_t)4608 * 1152 * 2);
    u16*   Wih2p = (u16*)alloc((size_t)1600 * 1152 * 2);
    u16*   Whh2p = (u16*)alloc((size_t)1600 * 416 * 2);
    float* bias0 = (float*)alloc((size_t)4608 * 4);
    float* bias1 = (float*)alloc((size_t)4608 * 4);
    float* bias2 = (float*)alloc((size_t)1600 * 4);
    u16*   hbuf  = (u16*)alloc((size_t)2 * 16 * 1152 * 2);
    float* cbuf  = (float*)alloc((size_t)16 * 1150 * 4);
    u16*   Wxp   = (u16*)alloc((size_t)416 * 416 * 2);
    float* wtv   = (float*)alloc((size_t)400 * 4);
    float* dwx   = (float*)alloc((size_t)400 * 4);
    float* dl    = (float*)alloc((size_t)NTOK * 4);
    float* e2    = (float*)alloc((size_t)NTOK * 4);
    float* uvec  = (float*)alloc((size_t)NTOK * 4);

    // output offsets
    size_t OM = (size_t)SEQL * NBATCH * NTOK;
    float* oh1 = out + OM;
    float* oc1 = oh1 + 16 * 1150;
    float* oh2 = oc1 + 16 * 1150;
    float* oc2 = oh2 + 16 * 1150;
    float* oh3 = oc2 + 16 * 1150;
    float* oc3 = oh3 + 16 * 400;

    // ---- zero padded buffers (pads must stay 0) ----
    hipMemsetAsync(ys0, 0, (size_t)1152 * 1152 * 2, stream);
    hipMemsetAsync(ys1, 0, (size_t)1152 * 1152 * 2, stream);
    hipMemsetAsync(ys2, 0, (size_t)1152 * 416 * 2, stream);
    hipMemsetAsync(hbuf, 0, (size_t)2 * 16 * 1152 * 2, stream);

    // ---- weight conversion / padding ----
    cvt_pad_k<<<2048, 256, 0, stream>>>(Wih0, Wih0p, 4, 1150, 1152, 400, 416, 400, 0);
    cvt_pad_k<<<2048, 256, 0, stream>>>(Whh0, Whh0p, 4, 1150, 1152, 1150, 1152, 1150, 0);
    cvt_pad_k<<<2048, 256, 0, stream>>>(Wih1, Wih1p, 4, 1150, 1152, 1150, 1152, 1150, 0);
    cvt_pad_k<<<2048, 256, 0, stream>>>(Whh1, Whh1p, 4, 1150, 1152, 1150, 1152, 1150, 0);
    cvt_pad_k<<<2048, 256, 0, stream>>>(Wih2, Wih2p, 4, 400, 400, 1150, 1152, 1150, 0);
    cvt_pad_k<<<2048, 256, 0, stream>>>(Whh2, Whh2p, 4, 400, 400, 400, 416, 400, 0);
    cvt_pad_k<<<2048, 256, 0, stream>>>(embW, emb_p, 1, 33278, 33280, 400, 416, 400, 0);
    cvt_pad_k<<<2048, 256, 0, stream>>>(cnfW, Wxp, 1, 400, 416, 400, 416, 401, 1);
    bias_k<<<(4 * 1152 + 255) / 256, 256, 0, stream>>>(bih0, bhh0, bias0, 1150, 1152);
    bias_k<<<(4 * 1152 + 255) / 256, 256, 0, stream>>>(bih1, bhh1, bias1, 1150, 1152);
    bias_k<<<(4 * 400 + 255) / 256, 256, 0, stream>>>(bih2, bhh2, bias2, 400, 400);
    wtdwx_k<<<2, 256, 0, stream>>>(cnfW, wtv, dwx);
    rowsumsq_k<<<NTOK, 64, 0, stream>>>(embW, e2, 400);

    // ---- CNF delta (independent of LSTM) ----
    cnf_k<<<520, 256, 0, stream>>>(embW, Wxp, wtv, cnfb, dwx, dl);
    ucomb_k<<<(NTOK + 255) / 256, 256, 0, stream>>>(e2, dl, uvec);

    // ---- embedding ----
    embed_k<<<(1152 * 416 + 255) / 256, 256, 0, stream>>>(tokens, embW, x0);

    // ---- layer 0 ----
    gemm_bt_k<<<dim3(72, 18), 256, 0, stream>>>(x0, Wih0p, xW, 416, 416, 416, 4608,
                                                1120, 4608, nullptr);
    h0cvt_k<<<(16 * 1152 + 255) / 256, 256, 0, stream>>>(h00, hbuf, 1150, 1152);
    hipMemcpyAsync(cbuf, c00, (size_t)16 * 1150 * 4, hipMemcpyDeviceToDevice, stream);
    for (int t = 0; t < SEQL; ++t) {
        const u16* hs = hbuf + (size_t)(t & 1) * 16 * 1152;
        u16* hd = hbuf + (size_t)((t + 1) & 1) * 16 * 1152;
        lstm_step_k<<<72, 256, 0, stream>>>(hs, Whh0p, xW + (size_t)t * 16 * 4608, bias0,
                                            cbuf, hd, ys0 + (size_t)t * 16 * 1152,
                                            1150, 1152, 1152, 1152);
    }
    copyhc_k<<<(16 * 1150 + 255) / 256, 256, 0, stream>>>(hbuf, cbuf, oh1, oc1, 1150, 1152);

    // ---- layer 1 ----
    gemm_bt_k<<<dim3(72, 18), 256, 0, stream>>>(ys0, Wih1p, xW, 1152, 1152, 1152, 4608,
                                                1120, 4608, nullptr);
    h0cvt_k<<<(16 * 1152 + 255) / 256, 256, 0, stream>>>(h01, hbuf, 1150, 1152);
    hipMemcpyAsync(cbuf, c01, (size_t)16 * 1150 * 4, hipMemcpyDeviceToDevice, stream);
    for (int t = 0; t < SEQL; ++t) {
        const u16* hs = hbuf + (size_t)(t & 1) * 16 * 1152;
        u16* hd = hbuf + (size_t)((t + 1) & 1) * 16 * 1152;
        lstm_step_k<<<72, 256, 0, stream>>>(hs, Whh1p, xW + (size_t)t * 16 * 4608, bias1,
                                            cbuf, hd, ys1 + (size_t)t * 16 * 1152,
                                            1150, 1152, 1152, 1152);
    }
    copyhc_k<<<(16 * 1150 + 255) / 256, 256, 0, stream>>>(hbuf, cbuf, oh2, oc2, 1150, 1152);

    // ---- layer 2 ----
    gemm_bt_k<<<dim3(25, 18), 256, 0, stream>>>(ys1, Wih2p, xW, 1152, 1152, 1152, 1600,
                                                1120, 1600, nullptr);
    hipMemsetAsync(hbuf, 0, (size_t)2 * 16 * 416 * 2, stream);  // layer2 uses stride 416
    h0cvt_k<<<(16 * 416 + 255) / 256, 256, 0, stream>>>(h02, hbuf, 400, 416);
    hipMemcpyAsync(cbuf, c02, (size_t)16 * 400 * 4, hipMemcpyDeviceToDevice, stream);
    for (int t = 0; t < SEQL; ++t) {
        const u16* hs = hbuf + (size_t)(t & 1) * 16 * 416;
        u16* hd = hbuf + (size_t)((t + 1) & 1) * 16 * 416;
        lstm_step_k<<<25, 256, 0, stream>>>(hs, Whh2p, xW + (size_t)t * 16 * 1600, bias2,
                                            cbuf, hd, ys2 + (size_t)t * 16 * 416,
                                            400, 400, 416, 416);
    }
    copyhc_k<<<(16 * 400 + 255) / 256, 256, 0, stream>>>(hbuf, cbuf, oh3, oc3, 400, 416);

    // ---- logits into d_out, then in-place log-softmax ----
    gemm_bt_k<<<dim3(520, 18), 256, 0, stream>>>(ys2, emb_p, out, 416, 416, 416, NTOK,
                                                 1120, NTOK, uvec);
    logsoftmax_k<<<1120, 256, 0, stream>>>(out, NTOK);
}

// Round 2
// 4145.733 us; speedup vs baseline: 1.3612x; 1.3612x over previous
//
#include <hip/hip_runtime.h>
#include <hip/hip_bf16.h>
#include <math.h>

#define SEQL 70
#define NBATCH 16
#define NINPD 400
#define NHIDD 1150
#define NTOK 33278
#define ODE_STEPS 8

typedef __attribute__((ext_vector_type(4))) float f32x4;
typedef __attribute__((ext_vector_type(8))) short s16x8;
typedef unsigned short u16;

__device__ __forceinline__ u16 f2b(float f) {
    union { float f; unsigned int u; } a; a.f = f;
    unsigned int u = a.u;
    return (u16)((u + 0x7FFFu + ((u >> 16) & 1u)) >> 16);
}
__device__ __forceinline__ float b2f(u16 s) {
    union { unsigned int u; float f; } a; a.u = ((unsigned int)s) << 16;
    return a.f;
}

// ---------- prep kernels ----------
__global__ void cvt_pad_k(const float* __restrict__ src, u16* __restrict__ dst,
                          int G, int Nin, int Nop, int Kin, int Kp, int rs, int co) {
    size_t total = (size_t)G * Nop * Kp;
    for (size_t idx = (size_t)blockIdx.x * 256 + threadIdx.x; idx < total;
         idx += (size_t)gridDim.x * 256) {
        int k = (int)(idx % Kp);
        size_t t2 = idx / Kp;
        int j = (int)(t2 % Nop);
        int g = (int)(t2 / Nop);
        float v = 0.f;
        if (j < Nin && k < Kin) v = src[((size_t)g * Nin + j) * rs + co + k];
        dst[idx] = f2b(v);
    }
}

__global__ void bias_k(const float* __restrict__ bih, const float* __restrict__ bhh,
                       float* __restrict__ o, int Nin, int Nop) {
    int idx = blockIdx.x * 256 + threadIdx.x;
    if (idx >= 4 * Nop) return;
    int g = idx / Nop, j = idx % Nop;
    o[idx] = (j < Nin) ? (bih[g * Nin + j] + bhh[g * Nin + j]) : 0.f;
}

__global__ void wtdwx_k(const float* __restrict__ cw, float* __restrict__ wt,
                        float* __restrict__ dwx) {
    int i = blockIdx.x * 256 + threadIdx.x;
    if (i < NINPD) {
        wt[i]  = cw[(size_t)i * (NINPD + 1)];
        dwx[i] = cw[(size_t)i * (NINPD + 1) + 1 + i];
    }
}

__global__ void h0cvt_k(const float* __restrict__ h0, u16* __restrict__ hb, int N, int Kp) {
    int idx = blockIdx.x * 256 + threadIdx.x;
    if (idx >= 16 * Kp) return;
    int b = idx / Kp, k = idx % Kp;
    hb[idx] = f2b(k < N ? h0[b * N + k] : 0.f);
}

__global__ void copyhc_k(const u16* __restrict__ hb, const float* __restrict__ cb,
                         float* __restrict__ oh, float* __restrict__ oc, int N, int Kp) {
    int idx = blockIdx.x * 256 + threadIdx.x;
    if (idx >= 16 * N) return;
    int b = idx / N, j = idx % N;
    oh[idx] = b2f(hb[b * Kp + j]);
    oc[idx] = cb[idx];
}

__global__ void embed_k(const int* __restrict__ tok, const float* __restrict__ emb,
                        u16* __restrict__ x0) {
    int idx = blockIdx.x * 256 + threadIdx.x;
    if (idx >= 1152 * 416) return;
    int r = idx / 416, k = idx - r * 416;
    float v = 0.f;
    if (r < SEQL * NBATCH && k < NINPD) v = emb[(size_t)tok[r] * NINPD + k];
    x0[idx] = f2b(v);
}

__global__ void rowsumsq_k(const float* __restrict__ X, float* __restrict__ o, int K) {
    int r = blockIdx.x;
    const float* xr = X + (size_t)r * K;
    int lane = threadIdx.x;
    float s = 0.f;
    for (int k = lane; k < K; k += 64) { float v = xr[k]; s += v * v; }
#pragma unroll
    for (int off = 1; off < 64; off <<= 1) s += __shfl_xor(s, off, 64);
    if (lane == 0) o[r] = s;
}

__global__ void ucomb_k(const float* __restrict__ e2, const float* __restrict__ dl,
                        float* __restrict__ u) {
    int i = blockIdx.x * 256 + threadIdx.x;
    if (i < NTOK) u[i] = -0.5f * e2[i] - dl[i];
}

// ---------- GEMM: C[M,N](fp32) = A[M,Kp](bf16) * B[N,Kp]^T(bf16) (+ u[n]) ----------
__global__ void gemm_bt_k(const u16* __restrict__ A, const u16* __restrict__ B,
                          float* __restrict__ C, int Kp, int lda, int ldb, int ldc,
                          int Mreal, int Nreal, const float* __restrict__ uvec) {
    const int tid = threadIdx.x;
    const int wid = tid >> 6, lane = tid & 63;
    const int la = lane & 15, lk = (lane >> 4) * 8;
    const int m0 = blockIdx.y * 64 + wid * 16;
    const int n0 = blockIdx.x * 64;
    const f32x4 Z4 = {0.f, 0.f, 0.f, 0.f};
    f32x4 acc[4] = {Z4, Z4, Z4, Z4};
    const u16* Ar = A + (size_t)(m0 + la) * lda + lk;
    const u16* Br = B + (size_t)(n0 + la) * ldb + lk;
    for (int k = 0; k < Kp; k += 32) {
        s16x8 a = *(const s16x8*)(Ar + k);
#pragma unroll
        for (int nt = 0; nt < 4; ++nt) {
            s16x8 b = *(const s16x8*)(Br + (size_t)nt * 16 * ldb + k);
            acc[nt] = __builtin_amdgcn_mfma_f32_16x16x32_bf16(a, b, acc[nt], 0, 0, 0);
        }
    }
    const int mr = m0 + (lane >> 4) * 4;
#pragma unroll
    for (int nt = 0; nt < 4; ++nt) {
        int cc = n0 + nt * 16 + la;
        if (cc >= Nreal) continue;
        float uv = uvec ? uvec[cc] : 0.f;
#pragma unroll
        for (int r = 0; r < 4; ++r) {
            int rr = mr + r;
            if (rr < Mreal) C[(size_t)rr * ldc + cc] = acc[nt][r] + uv;
        }
    }
}

// ---------- LSTM step ----------
__global__ void lstm_step_k(const u16* __restrict__ hsrc, const u16* __restrict__ Whh,
                            const float* __restrict__ xW, const float* __restrict__ bias,
                            float* __restrict__ c, u16* __restrict__ hdst,
                            u16* __restrict__ ys, int N, int Np, int Kp, int Kp2) {
    __shared__ float gl[4][16][16];
    const int tid = threadIdx.x;
    const int wid = tid >> 6, lane = tid & 63;
    const int la = lane & 15, lk = (lane >> 4) * 8;
    const int jb = blockIdx.x;
    const f32x4 Z4 = {0.f, 0.f, 0.f, 0.f};
    f32x4 acc = Z4;
    const u16* Ar = hsrc + (size_t)la * Kp + lk;
    const u16* Br = Whh + (size_t)(wid * Np + jb * 16 + la) * Kp + lk;
    for (int k = 0; k < Kp; k += 32) {
        s16x8 a = *(const s16x8*)(Ar + k);
        s16x8 b = *(const s16x8*)(Br + k);
        acc = __builtin_amdgcn_mfma_f32_16x16x32_bf16(a, b, acc, 0, 0, 0);
    }
    const int col = jb * 16 + la;
    const int b4 = (lane >> 4) * 4;
#pragma unroll
    for (int r = 0; r < 4; ++r) {
        int bb = b4 + r;
        gl[wid][bb][la] = acc[r] + xW[(size_t)bb * (4 * Np) + wid * Np + col]
                          + bias[wid * Np + col];
    }
    __syncthreads();
    const int tb = tid >> 4, tj = tid & 15;
    const int j = jb * 16 + tj;
    if (j < N) {
        float gi = gl[0][tb][tj], gf = gl[1][tb][tj];
        float gg = gl[2][tb][tj], go = gl[3][tb][tj];
        float si = 1.f / (1.f + expf(-gi));
        float sf = 1.f / (1.f + expf(-gf));
        float so = 1.f / (1.f + expf(-go));
        float cn = sf * c[tb * N + j] + si * tanhf(gg);
        float hn = so * tanhf(cn);
        c[tb * N + j] = cn;
        u16 hb16 = f2b(hn);
        hdst[tb * Kp2 + j] = hb16;
        ys[tb * Kp2 + j] = hb16;
    }
}

// ---------- fused CNF v2 ----------
// 512 threads = 8 waves; each wave: all 4 m-tiles x its n-slice of 25 tiles.
// z0 fp32 in LDS (stride 418, conflict-free); eval state bf16 in LDS (XOR swizzle);
// RK4 accumulator in registers.
#define Z0S 418
__device__ __forceinline__ unsigned zoff(int row, int colb) {
    unsigned s = ((colb < 768 ? (row & 7) : (row & 3)) << 4);
    return (unsigned)(row * 832 + (colb ^ (int)s));
}

__global__ __launch_bounds__(512, 2) void cnf_k(const float* __restrict__ emb,
                                                const u16* __restrict__ Wxp,
                                                const float* __restrict__ wt,
                                                const float* __restrict__ bv,
                                                const float* __restrict__ dwx,
                                                float* __restrict__ dl) {
    __shared__ float z0s[64 * Z0S];
    __shared__ __align__(16) u16 zi[64 * 416];
    const int tid = threadIdx.x;
    const int m0 = blockIdx.x * 64;

    // staging
    for (int idx = tid; idx < 64 * 416; idx += 512) {
        int r = idx / 416, cc = idx - r * 416;
        int row = m0 + r;
        float v = (cc < 400 && row < NTOK) ? emb[(size_t)row * 400 + cc] : 0.f;
        if (cc < 416) z0s[r * Z0S + cc] = v;
        *(u16*)((char*)zi + zoff(r, cc * 2)) = f2b(v);
    }

    const int wv = tid >> 6, lane = tid & 63;
    const int la = lane & 15, lg = lane >> 4;
    const int lk = lg * 8;
    const int Qw = (wv == 0) ? 4 : 3;
    const int ntb = (wv == 0) ? 0 : 4 + (wv - 1) * 3;

    float wtq[4], bq[4], dwq[4];
#pragma unroll
    for (int q = 0; q < 4; ++q) {
        if (q < Qw) {
            int col = (ntb + q) * 16 + la;
            wtq[q] = wt[col]; bq[q] = bv[col]; dwq[q] = dwx[col];
        } else { wtq[q] = 0.f; bq[q] = 0.f; dwq[q] = 0.f; }
    }
    __syncthreads();

    const float dt = 1.f / ODE_STEPS;
    const f32x4 Z4 = {0.f, 0.f, 0.f, 0.f};
    float Aacc[4][4][4];
#pragma unroll
    for (int m = 0; m < 4; ++m)
#pragma unroll
        for (int q = 0; q < 4; ++q)
#pragma unroll
            for (int r = 0; r < 4; ++r) Aacc[m][q][r] = 0.f;
    float divp[4][4];
#pragma unroll
    for (int m = 0; m < 4; ++m)
#pragma unroll
        for (int r = 0; r < 4; ++r) divp[m][r] = 0.f;

#pragma unroll 1
    for (int st = 0; st < ODE_STEPS; ++st) {
        float t0 = st * dt;
#pragma unroll 1
        for (int s = 0; s < 4; ++s) {
            float ts = t0 + ((s == 0) ? 0.f : (s == 3) ? dt : 0.5f * dt);
            float wgt = (s == 1 || s == 2) ? 2.f : 1.f;
            float cs = (s == 2) ? dt : 0.5f * dt;
            f32x4 pre[4][4];
#pragma unroll
            for (int m = 0; m < 4; ++m)
#pragma unroll
                for (int q = 0; q < 4; ++q) pre[m][q] = Z4;
#pragma unroll 1
            for (int kk = 0; kk < 13; ++kk) {
                s16x8 b[4];
#pragma unroll
                for (int q = 0; q < 4; ++q)
                    if (q < Qw)
                        b[q] = *(const s16x8*)(Wxp + (size_t)((ntb + q) * 16 + la) * 416 +
                                               kk * 32 + lk);
#pragma unroll
                for (int m = 0; m < 4; ++m) {
                    int row = m * 16 + la;
                    s16x8 a = *(const s16x8*)((const char*)zi +
                                              zoff(row, kk * 64 + lg * 16));
#pragma unroll
                    for (int q = 0; q < 4; ++q)
                        if (q < Qw)
                            pre[m][q] = __builtin_amdgcn_mfma_f32_16x16x32_bf16(
                                a, b[q], pre[m][q], 0, 0, 0);
                }
            }
            __syncthreads();
#pragma unroll
            for (int m = 0; m < 4; ++m) {
#pragma unroll
                for (int q = 0; q < 4; ++q) {
                    if (q >= Qw) continue;
                    int col = (ntb + q) * 16 + la;
#pragma unroll
                    for (int r = 0; r < 4; ++r) {
                        int row = m * 16 + lg * 4 + r;
                        float pv = pre[m][q][r] + ts * wtq[q] + bq[q];
                        float kz = fmaxf(pv, 0.f);
                        if (pv > 0.f) divp[m][r] += dwq[q] * wgt;
                        float An = Aacc[m][q][r] + wgt * kz;
                        float ev;
                        if (s < 3) {
                            Aacc[m][q][r] = An;
                            ev = z0s[row * Z0S + col] + cs * kz;
                        } else {
                            float zn = z0s[row * Z0S + col] + (dt / 6.f) * An;
                            z0s[row * Z0S + col] = zn;
                            Aacc[m][q][r] = 0.f;
                            ev = zn;
                        }
                        *(u16*)((char*)zi + zoff(row, col * 2)) = f2b(ev);
                    }
                }
            }
            __syncthreads();
        }
    }

    // divergence reduce: sum over la lanes (cols within wave), then across waves via LDS
#pragma unroll
    for (int m = 0; m < 4; ++m)
#pragma unroll
        for (int r = 0; r < 4; ++r) {
            float v = divp[m][r];
            v += __shfl_xor(v, 1, 64);
            v += __shfl_xor(v, 2, 64);
            v += __shfl_xor(v, 4, 64);
            v += __shfl_xor(v, 8, 64);
            divp[m][r] = v;
        }
    float* dsc = (float*)zi;  // zi no longer needed
    if (la == 0) {
#pragma unroll
        for (int m = 0; m < 4; ++m)
#pragma unroll
            for (int r = 0; r < 4; ++r)
                dsc[wv * 64 + m * 16 + lg * 4 + r] = divp[m][r];
    }
    __syncthreads();
    for (int row = tid; row < 64; row += 512) {
        float s = 0.f;
#pragma unroll
        for (int w = 0; w < 8; ++w) s += dsc[w * 64 + row];
        if (m0 + row < NTOK) dl[m0 + row] = -(dt / 6.f) * s;
    }
}

// ---------- in-place log(softmax(x)+1e-8) per row ----------
__global__ void logsoftmax_k(float* __restrict__ L, int n) {
    const int row = blockIdx.x;
    float* R = L + (size_t)row * n;
    const int tid = threadIdx.x;
    float mx = -INFINITY, s = 0.f;
    for (int c = tid; c < n; c += 256) {
        float v = R[c];
        float nm = fmaxf(mx, v);
        s = s * expf(mx - nm) + expf(v - nm);
        mx = nm;
    }
#pragma unroll
    for (int off = 1; off < 64; off <<= 1) {
        float om = __shfl_xor(mx, off, 64);
        float os = __shfl_xor(s, off, 64);
        float nm = fmaxf(mx, om);
        s = s * expf(mx - nm) + os * expf(om - nm);
        mx = nm;
    }
    __shared__ float smx[4], ssm[4];
    if ((tid & 63) == 0) { smx[tid >> 6] = mx; ssm[tid >> 6] = s; }
    __syncthreads();
    float bm = fmaxf(fmaxf(smx[0], smx[1]), fmaxf(smx[2], smx[3]));
    float bs = ssm[0] * expf(smx[0] - bm) + ssm[1] * expf(smx[1] - bm) +
               ssm[2] * expf(smx[2] - bm) + ssm[3] * expf(smx[3] - bm);
    float lz = logf(bs);
    for (int c = tid; c < n; c += 256) {
        float v = R[c];
        R[c] = logf(expf(v - bm) + 1e-8f * bs) - lz;
    }
}

extern "C" void kernel_launch(void* const* d_in, const int* in_sizes, int n_in,
                              void* d_out, int out_size, void* d_ws, size_t ws_size,
                              hipStream_t stream) {
    const int*   tokens = (const int*)d_in[0];
    const float* h00 = (const float*)d_in[1];
    const float* c00 = (const float*)d_in[2];
    const float* h01 = (const float*)d_in[3];
    const float* c01 = (const float*)d_in[4];
    const float* h02 = (const float*)d_in[5];
    const float* c02 = (const float*)d_in[6];
    const float* embW = (const float*)d_in[7];
    const float* Wih0 = (const float*)d_in[8];
    const float* Whh0 = (const float*)d_in[9];
    const float* bih0 = (const float*)d_in[10];
    const float* bhh0 = (const float*)d_in[11];
    const float* Wih1 = (const float*)d_in[12];
    const float* Whh1 = (const float*)d_in[13];
    const float* bih1 = (const float*)d_in[14];
    const float* bhh1 = (const float*)d_in[15];
    const float* Wih2 = (const float*)d_in[16];
    const float* Whh2 = (const float*)d_in[17];
    const float* bih2 = (const float*)d_in[18];
    const float* bhh2 = (const float*)d_in[19];
    const float* cnfW = (const float*)d_in[20];
    const float* cnfb = (const float*)d_in[21];
    float* out = (float*)d_out;

    char* p = (char*)d_ws;
    auto alloc = [&](size_t bytes) -> void* {
        void* r = (void*)p;
        p += (bytes + 255) & ~(size_t)255;
        return r;
    };
    u16*   emb_p = (u16*)alloc((size_t)33280 * 416 * 2);
    u16*   x0    = (u16*)alloc((size_t)1152 * 416 * 2);
    u16*   ys0   = (u16*)alloc((size_t)1152 * 1152 * 2);
    u16*   ys1   = (u16*)alloc((size_t)1152 * 1152 * 2);
    u16*   ys2   = (u16*)alloc((size_t)1152 * 416 * 2);
    float* xW    = (float*)alloc((size_t)1120 * 4608 * 4);
    u16*   Wih0p = (u16*)alloc((size_t)4608 * 416 * 2);
    u16*   Whh0p = (u16*)alloc((size_t)4608 * 1152 * 2);
    u16*   Wih1p = (u16*)alloc((size_t)4608 * 1152 * 2);
    u16*   Whh1p = (u16*)alloc((size_t)4608 * 1152 * 2);
    u16*   Wih2p = (u16*)alloc((size_t)1600 * 1152 * 2);
    u16*   Whh2p = (u16*)alloc((size_t)1600 * 416 * 2);
    float* bias0 = (float*)alloc((size_t)4608 * 4);
    float* bias1 = (float*)alloc((size_t)4608 * 4);
    float* bias2 = (float*)alloc((size_t)1600 * 4);
    u16*   hbuf  = (u16*)alloc((size_t)2 * 16 * 1152 * 2);
    float* cbuf  = (float*)alloc((size_t)16 * 1150 * 4);
    u16*   Wxp   = (u16*)alloc((size_t)416 * 416 * 2);
    float* wtv   = (float*)alloc((size_t)400 * 4);
    float* dwx   = (float*)alloc((size_t)400 * 4);
    float* dl    = (float*)alloc((size_t)NTOK * 4);
    float* e2    = (float*)alloc((size_t)NTOK * 4);
    float* uvec  = (float*)alloc((size_t)NTOK * 4);

    size_t OM = (size_t)SEQL * NBATCH * NTOK;
    float* oh1 = out + OM;
    float* oc1 = oh1 + 16 * 1150;
    float* oh2 = oc1 + 16 * 1150;
    float* oc2 = oh2 + 16 * 1150;
    float* oh3 = oc2 + 16 * 1150;
    float* oc3 = oh3 + 16 * 400;

    hipMemsetAsync(ys0, 0, (size_t)1152 * 1152 * 2, stream);
    hipMemsetAsync(ys1, 0, (size_t)1152 * 1152 * 2, stream);
    hipMemsetAsync(ys2, 0, (size_t)1152 * 416 * 2, stream);
    hipMemsetAsync(hbuf, 0, (size_t)2 * 16 * 1152 * 2, stream);

    cvt_pad_k<<<2048, 256, 0, stream>>>(Wih0, Wih0p, 4, 1150, 1152, 400, 416, 400, 0);
    cvt_pad_k<<<2048, 256, 0, stream>>>(Whh0, Whh0p, 4, 1150, 1152, 1150, 1152, 1150, 0);
    cvt_pad_k<<<2048, 256, 0, stream>>>(Wih1, Wih1p, 4, 1150, 1152, 1150, 1152, 1150, 0);
    cvt_pad_k<<<2048, 256, 0, stream>>>(Whh1, Whh1p, 4, 1150, 1152, 1150, 1152, 1150, 0);
    cvt_pad_k<<<2048, 256, 0, stream>>>(Wih2, Wih2p, 4, 400, 400, 1150, 1152, 1150, 0);
    cvt_pad_k<<<2048, 256, 0, stream>>>(Whh2, Whh2p, 4, 400, 400, 400, 416, 400, 0);
    cvt_pad_k<<<2048, 256, 0, stream>>>(embW, emb_p, 1, 33278, 33280, 400, 416, 400, 0);
    cvt_pad_k<<<2048, 256, 0, stream>>>(cnfW, Wxp, 1, 400, 416, 400, 416, 401, 1);
    bias_k<<<(4 * 1152 + 255) / 256, 256, 0, stream>>>(bih0, bhh0, bias0, 1150, 1152);
    bias_k<<<(4 * 1152 + 255) / 256, 256, 0, stream>>>(bih1, bhh1, bias1, 1150, 1152);
    bias_k<<<(4 * 400 + 255) / 256, 256, 0, stream>>>(bih2, bhh2, bias2, 400, 400);
    wtdwx_k<<<2, 256, 0, stream>>>(cnfW, wtv, dwx);
    rowsumsq_k<<<NTOK, 64, 0, stream>>>(embW, e2, 400);

    cnf_k<<<520, 512, 0, stream>>>(embW, Wxp, wtv, cnfb, dwx, dl);
    ucomb_k<<<(NTOK + 255) / 256, 256, 0, stream>>>(e2, dl, uvec);

    embed_k<<<(1152 * 416 + 255) / 256, 256, 0, stream>>>(tokens, embW, x0);

    // layer 0
    gemm_bt_k<<<dim3(72, 18), 256, 0, stream>>>(x0, Wih0p, xW, 416, 416, 416, 4608,
                                                1120, 4608, nullptr);
    h0cvt_k<<<(16 * 1152 + 255) / 256, 256, 0, stream>>>(h00, hbuf, 1150, 1152);
    hipMemcpyAsync(cbuf, c00, (size_t)16 * 1150 * 4, hipMemcpyDeviceToDevice, stream);
    for (int t = 0; t < SEQL; ++t) {
        const u16* hs = hbuf + (size_t)(t & 1) * 16 * 1152;
        u16* hd = hbuf + (size_t)((t + 1) & 1) * 16 * 1152;
        lstm_step_k<<<72, 256, 0, stream>>>(hs, Whh0p, xW + (size_t)t * 16 * 4608, bias0,
                                            cbuf, hd, ys0 + (size_t)t * 16 * 1152,
                                            1150, 1152, 1152, 1152);
    }
    copyhc_k<<<(16 * 1150 + 255) / 256, 256, 0, stream>>>(hbuf, cbuf, oh1, oc1, 1150, 1152);

    // layer 1
    gemm_bt_k<<<dim3(72, 18), 256, 0, stream>>>(ys0, Wih1p, xW, 1152, 1152, 1152, 4608,
                                                1120, 4608, nullptr);
    h0cvt_k<<<(16 * 1152 + 255) / 256, 256, 0, stream>>>(h01, hbuf, 1150, 1152);
    hipMemcpyAsync(cbuf, c01, (size_t)16 * 1150 * 4, hipMemcpyDeviceToDevice, stream);
    for (int t = 0; t < SEQL; ++t) {
        const u16* hs = hbuf + (size_t)(t & 1) * 16 * 1152;
        u16* hd = hbuf + (size_t)((t + 1) & 1) * 16 * 1152;
        lstm_step_k<<<72, 256, 0, stream>>>(hs, Whh1p, xW + (size_t)t * 16 * 4608, bias1,
                                            cbuf, hd, ys1 + (size_t)t * 16 * 1152,
                                            1150, 1152, 1152, 1152);
    }
    copyhc_k<<<(16 * 1150 + 255) / 256, 256, 0, stream>>>(hbuf, cbuf, oh2, oc2, 1150, 1152);

    // layer 2
    gemm_bt_k<<<dim3(25, 18), 256, 0, stream>>>(ys1, Wih2p, xW, 1152, 1152, 1152, 1600,
                                                1120, 1600, nullptr);
    hipMemsetAsync(hbuf, 0, (size_t)2 * 16 * 416 * 2, stream);
    h0cvt_k<<<(16 * 416 + 255) / 256, 256, 0, stream>>>(h02, hbuf, 400, 416);
    hipMemcpyAsync(cbuf, c02, (size_t)16 * 400 * 4, hipMemcpyDeviceToDevice, stream);
    for (int t = 0; t < SEQL; ++t) {
        const u16* hs = hbuf + (size_t)(t & 1) * 16 * 416;
        u16* hd = hbuf + (size_t)((t + 1) & 1) * 16 * 416;
        lstm_step_k<<<25, 256, 0, stream>>>(hs, Whh2p, xW + (size_t)t * 16 * 1600, bias2,
                                            cbuf, hd, ys2 + (size_t)t * 16 * 416,
                                            400, 400, 416, 416);
    }
    copyhc_k<<<(16 * 400 + 255) / 256, 256, 0, stream>>>(hbuf, cbuf, oh3, oc3, 400, 416);

    gemm_bt_k<<<dim3(520, 18), 256, 0, stream>>>(ys2, emb_p, out, 416, 416, 416, NTOK,
                                                 1120, NTOK, uvec);
    logsoftmax_k<<<1120, 256, 0, stream>>>(out, NTOK);
}